// Round 4
// baseline (1117.804 us; speedup 1.0000x reference)
//
#include <hip/hip_runtime.h>
#include <math.h>

#define INC    128
#define HID    32
#define NSEG   16
#define SPG    4                 // segments per group: ~128 MB of feats << 256 MB L3
#define NGRP   (NSEG / SPG)      // 4 groups
#define NBLK   2048

// ---- non-temporal 16B store: out must not evict group feats from L3 --------
typedef float f4v __attribute__((ext_vector_type(4)));
__device__ __forceinline__ void ntstore4(float4* p, float4 f) {
    f4v v = {f.x, f.y, f.z, f.w};
    __builtin_nontemporal_store(v, (f4v*)p);
}

// Order-preserving float <-> uint mapping so unsigned atomicMax works for
// float max (handles negatives; encode(any real) > 0, so a zero-initialized
// accumulator is a valid identity).
__device__ __forceinline__ unsigned f2ord(float f) {
    unsigned u = __float_as_uint(f);
    return (u & 0x80000000u) ? ~u : (u | 0x80000000u);
}
__device__ __forceinline__ float ord2f(unsigned u) {
    return (u & 0x80000000u) ? __uint_as_float(u & 0x7fffffffu)
                             : __uint_as_float(~u);
}

// first index i in [0,n) with a[i] >= v   (bidx is sorted)
__device__ __forceinline__ int lower_bound(const int* __restrict__ a, int n, int v) {
    int lo = 0, hi = n;
    while (lo < hi) { int m = (lo + hi) >> 1; if (a[m] < v) lo = m + 1; else hi = m; }
    return lo;
}

__device__ __forceinline__ void flush_lds8(int sseg, int c8,
                                           const float4& s0, const float4& s1,
                                           const float4& m0, const float4& m1,
                                           float cnt, float* s_sum,
                                           unsigned* s_max, float* s_cnt) {
    int base = sseg * INC + c8 * 8;
    atomicAdd(&s_sum[base + 0], s0.x);  atomicAdd(&s_sum[base + 1], s0.y);
    atomicAdd(&s_sum[base + 2], s0.z);  atomicAdd(&s_sum[base + 3], s0.w);
    atomicAdd(&s_sum[base + 4], s1.x);  atomicAdd(&s_sum[base + 5], s1.y);
    atomicAdd(&s_sum[base + 6], s1.z);  atomicAdd(&s_sum[base + 7], s1.w);
    atomicMax(&s_max[base + 0], f2ord(m0.x));  atomicMax(&s_max[base + 1], f2ord(m0.y));
    atomicMax(&s_max[base + 2], f2ord(m0.z));  atomicMax(&s_max[base + 3], f2ord(m0.w));
    atomicMax(&s_max[base + 4], f2ord(m1.x));  atomicMax(&s_max[base + 5], f2ord(m1.y));
    atomicMax(&s_max[base + 6], f2ord(m1.z));  atomicMax(&s_max[base + 7], f2ord(m1.w));
    if (c8 == 0) atomicAdd(&s_cnt[sseg], cnt);
}

// ---------------- Kernel A: segment sum/max/count for ONE group -------------
// Rows of group = [lower_bound(seg_lo), lower_bound(seg_lo+SPG)) since bidx is
// sorted. Cached (non-nt) loads on purpose: they populate L3 so the paired
// apply launch re-reads them at L3 speed.
__global__ __launch_bounds__(256) void seg_reduce_group(
    const float4* __restrict__ feats4, const int* __restrict__ bidx,
    float* __restrict__ gsum, unsigned* __restrict__ gmax,
    float* __restrict__ gcnt, int nrows, int seg_lo)
{
    __shared__ float    s_sum[SPG * INC];
    __shared__ unsigned s_max[SPG * INC];
    __shared__ float    s_cnt[SPG];
    __shared__ int      s_bounds[2];

    const int tid = threadIdx.x;
    if (tid < 2) s_bounds[tid] = lower_bound(bidx, nrows, seg_lo + tid * SPG);
    for (int i = tid; i < SPG * INC; i += 256) { s_sum[i] = 0.f; s_max[i] = 0u; }
    if (tid < SPG) s_cnt[tid] = 0.f;
    __syncthreads();

    const int r0 = s_bounds[0], r1 = s_bounds[1];
    if (r1 <= r0) return;                               // empty group (uniform)
    const int chunk = (r1 - r0 + NBLK - 1) / NBLK;
    const int rs = min(r0 + (int)blockIdx.x * chunk, r1);
    const int re = min(rs + chunk, r1);
    if (rs >= re) return;                               // uniform per block

    const int c8   = tid & 15;   // 8-float column group (16 lanes cover a row)
    const int slot = tid >> 4;   // 16 rows per block-iteration
    int    cur = -1;
    float4 s0 = make_float4(0.f, 0.f, 0.f, 0.f), s1 = s0;
    float4 m0 = s0, m1 = s0;
    float  cnt = 0.f;

    for (int r = rs + slot; r < re; r += 16) {
        int           seg  = bidx[r];
        const float4* rowp = feats4 + (size_t)r * 32 + c8 * 2;
        float4        f0   = rowp[0];
        float4        f1   = rowp[1];
        if (seg != cur) {
            if (cur >= 0) flush_lds8(cur - seg_lo, c8, s0, s1, m0, m1, cnt,
                                     s_sum, s_max, s_cnt);
            cur = seg; s0 = f0; s1 = f1; m0 = f0; m1 = f1; cnt = 1.f;
        } else {
            s0.x += f0.x; s0.y += f0.y; s0.z += f0.z; s0.w += f0.w;
            s1.x += f1.x; s1.y += f1.y; s1.z += f1.z; s1.w += f1.w;
            m0.x = fmaxf(m0.x, f0.x); m0.y = fmaxf(m0.y, f0.y);
            m0.z = fmaxf(m0.z, f0.z); m0.w = fmaxf(m0.w, f0.w);
            m1.x = fmaxf(m1.x, f1.x); m1.y = fmaxf(m1.y, f1.y);
            m1.z = fmaxf(m1.z, f1.z); m1.w = fmaxf(m1.w, f1.w);
            cnt += 1.f;
        }
    }
    if (cur >= 0) flush_lds8(cur - seg_lo, c8, s0, s1, m0, m1, cnt,
                             s_sum, s_max, s_cnt);
    __syncthreads();

    // Global flush: segments present in [rs, re) form a contiguous range.
    const int sf  = bidx[rs] - seg_lo;
    const int sl  = bidx[re - 1] - seg_lo;
    const int col = tid & (INC - 1);
    for (int s = sf + (tid >> 7); s <= sl; s += 2) {
        atomicAdd(&gsum[(seg_lo + s) * INC + col], s_sum[s * INC + col]);
        atomicMax(&gmax[(seg_lo + s) * INC + col], s_max[s * INC + col]);
        if (col == 0) atomicAdd(&gcnt[seg_lo + s], s_cnt[s]);
    }
}

// ---------------- Kernel B: per-block MLP + apply for ONE group -------------
// Runs after seg_reduce_group(g) on the same stream: kernel boundary = free
// grid-wide sync + device-scope visibility of the atomics. Each block computes
// gates only for the 1-2 segments its contiguous row chunk touches (stats and
// weights are tiny and L2-hot), then streams feats (L3 hits) * gate -> out.
__global__ __launch_bounds__(256) void apply_group(
    const float4* __restrict__ feats4, const int* __restrict__ bidx,
    const float* __restrict__ gsum, const unsigned* __restrict__ gmax,
    const float* __restrict__ gcnt,
    const float* __restrict__ W1, const float* __restrict__ b1,
    const float* __restrict__ W2, const float* __restrict__ b2,
    float4* __restrict__ out4, int nrows, int seg_lo)
{
    __shared__ float4 s_gate[SPG * (INC / 4)];   // gates for this group's segs
    __shared__ float  s_row[2 * INC];            // mean | max for one segment
    __shared__ float  s_hh[2 * HID];             // relu(h_mean) | relu(h_max)
    __shared__ int    s_bounds[2];

    const int tid = threadIdx.x;
    if (tid < 2) s_bounds[tid] = lower_bound(bidx, nrows, seg_lo + tid * SPG);
    __syncthreads();

    const int r0 = s_bounds[0], r1 = s_bounds[1];
    if (r1 <= r0) return;
    const int chunk = (r1 - r0 + NBLK - 1) / NBLK;
    const int rs = min(r0 + (int)blockIdx.x * chunk, r1);
    const int re = min(rs + chunk, r1);
    if (rs >= re) return;                        // uniform per block

    // gate = sigmoid(mlp(mean) + mlp(max));   b2 appears in BOTH mlps.
    const int sf = bidx[rs], sl = bidx[re - 1];
    for (int s = sf; s <= sl; ++s) {
        if (tid < INC) {
            float c = gcnt[s];
            s_row[tid]       = gsum[s * INC + tid] / fmaxf(c, 1.f);
            s_row[INC + tid] = (c > 0.f) ? ord2f(gmax[s * INC + tid]) : 0.f;
        }
        __syncthreads();
        if (tid < 2 * HID) {
            int h = tid & (HID - 1);
            const float* src = s_row + ((tid < HID) ? 0 : INC);
            float a = b1[h];
            for (int c = 0; c < INC; ++c) a += src[c] * W1[c * HID + h];
            s_hh[tid] = fmaxf(a, 0.f);
        }
        __syncthreads();
        if (tid < INC) {
            float a = 2.f * b2[tid];
            for (int h = 0; h < HID; ++h)
                a += (s_hh[h] + s_hh[HID + h]) * W2[h * INC + tid];
            ((float*)s_gate)[(s - seg_lo) * INC + tid] = 1.f / (1.f + expf(-a));
        }
        __syncthreads();
    }

    for (int i = rs * 32 + tid; i < re * 32; i += 256) {
        int    r   = i >> 5;
        int    c4  = i & 31;
        int    sg  = bidx[r] - seg_lo;
        float4 f   = feats4[(size_t)i];          // L3 hit: streamed in by reduce
        float4 g   = s_gate[sg * 32 + c4];
        ntstore4(&out4[(size_t)i],
                 make_float4(f.x * g.x, f.y * g.y, f.z * g.z, f.w * g.w));
    }
}

extern "C" void kernel_launch(void* const* d_in, const int* in_sizes, int n_in,
                              void* d_out, int out_size, void* d_ws, size_t ws_size,
                              hipStream_t stream) {
    const float4* feats4 = (const float4*)d_in[0];
    const int*    bidx   = (const int*)d_in[1];
    const float*  W1     = (const float*)d_in[2];
    const float*  b1     = (const float*)d_in[3];
    const float*  W2     = (const float*)d_in[4];
    const float*  b2     = (const float*)d_in[5];
    float4*       out4   = (float4*)d_out;
    const int     nrows  = in_sizes[1];          // N from batch_idx

    // Workspace (re-poisoned to 0xAA each call -> must memset):
    //   [0,      8192)  gsum  float[16*128]
    //   [8192,  16384)  gmax  uint [16*128]  (order-mapped)
    //   [16384, 16448)  gcnt  float[16]
    char*     ws   = (char*)d_ws;
    float*    gsum = (float*)(ws);
    unsigned* gmax = (unsigned*)(ws + 8192);
    float*    gcnt = (float*)(ws + 16384);

    hipMemsetAsync(d_ws, 0, 16448, stream);

    for (int g = 0; g < NGRP; ++g) {
        seg_reduce_group<<<NBLK, 256, 0, stream>>>(
            feats4, bidx, gsum, gmax, gcnt, nrows, g * SPG);
        apply_group<<<NBLK, 256, 0, stream>>>(
            feats4, bidx, gsum, gmax, gcnt, W1, b1, W2, b2, out4, nrows, g * SPG);
    }
}